// Round 2
// baseline (1708.087 us; speedup 1.0000x reference)
//
#include <hip/hip_runtime.h>
#include <math.h>

namespace {
constexpr int kBatch = 32, kH = 56, kW = 56, kC = 192, kNH = 6, kWS = 7, kSS = 3;
constexpr int kL   = kH * kW;        // 3136
constexpr int kN   = kWS * kWS;      // 49
constexpr int kTok = kBatch * kL;    // 100352
constexpr int kNWin = kTok / kN;     // 2048 windows
constexpr float kEps   = 1e-3f;
constexpr float kScale = 0.17677669529663687f;  // HD^-0.5
}

typedef unsigned short u16;
struct alignas(8) U16x4 { u16 x, y, z, w; };

__device__ __forceinline__ float bf2f(u16 u) {
    return __uint_as_float(((unsigned int)u) << 16);
}
__device__ __forceinline__ u16 f2bf(float f) {  // round-to-nearest-even
    unsigned int x = __float_as_uint(f);
    return (u16)((x + 0x7FFFu + ((x >> 16) & 1u)) >> 16);
}

// ---------------------------------------------------------------------------
// LayerNorm over C=192 (fp32 in, bf16 out), one wave per token.
// do_shift=1: write into cyclic-shifted + window-partitioned layout.
// ---------------------------------------------------------------------------
__global__ __launch_bounds__(256) void ln_kernel(
    const float* __restrict__ x, const float* __restrict__ gamma,
    const float* __restrict__ beta, u16* __restrict__ out, int do_shift)
{
    const int wave = threadIdx.x >> 6;
    const int lane = threadIdx.x & 63;
    const int tok = (blockIdx.x << 2) + wave;
    const float* xp = x + (size_t)tok * kC;
    float v0 = xp[lane], v1 = xp[lane + 64], v2 = xp[lane + 128];
    float s  = v0 + v1 + v2;
    float sq = v0 * v0 + v1 * v1 + v2 * v2;
    #pragma unroll
    for (int off = 32; off > 0; off >>= 1) {
        s  += __shfl_down(s, off, 64);
        sq += __shfl_down(sq, off, 64);
    }
    s  = __shfl(s, 0, 64);
    sq = __shfl(sq, 0, 64);
    const float mean = s * (1.0f / kC);
    const float var  = sq * (1.0f / kC) - mean * mean;
    const float inv  = rsqrtf(var + kEps);
    size_t orow;
    if (do_shift) {
        const int b = tok / kL, hw = tok % kL;
        const int h = hw / kW, w = hw % kW;
        const int hs = (h + kH - kSS) % kH;
        const int ws = (w + kW - kSS) % kW;
        const int wh = hs / kWS, ii = hs % kWS;
        const int ww = ws / kWS, jj = ws % kWS;
        orow = (size_t)(b * 64 + wh * 8 + ww) * kN + (ii * kWS + jj);
    } else {
        orow = tok;
    }
    u16* op = out + orow * kC;
    op[lane]       = f2bf((v0 - mean) * inv * gamma[lane]       + beta[lane]);
    op[lane + 64]  = f2bf((v1 - mean) * inv * gamma[lane + 64]  + beta[lane + 64]);
    op[lane + 128] = f2bf((v2 - mean) * inv * gamma[lane + 128] + beta[lane + 128]);
}

// ---------------------------------------------------------------------------
// GEMM: out(M x Nn) = A_bf16(M x K) @ Bw_f32(K-rows, ldB) + bias, epilogues:
// MODE 0: plain, bf16 out              MODE 1: exact GELU, bf16 out
// MODE 2: scatter (window-reverse+unshift) + residual aux(=x), fp32 out
// MODE 3: +bias +aux(same row), fp32 out   MODE 4: accumulate into out, fp32
// 256 thr, 64x64 tile, BK=16, 4x4 micro-tile. All dims divide evenly.
// ---------------------------------------------------------------------------
template <int MODE>
__global__ __launch_bounds__(256) void gemm_k(
    const u16* __restrict__ A, const float* __restrict__ Bw, int ldB,
    const float* __restrict__ bias, const float* __restrict__ aux,
    void* __restrict__ outv, int Nn, int K)
{
    __shared__ float As[64][20];
    __shared__ float Bs[16][64];
    const int tid = threadIdx.x;
    const int bm = blockIdx.y << 6;
    const int bn = blockIdx.x << 6;
    const int tr = tid >> 4;
    const int tc = tid & 15;
    const int ar = tid >> 2;
    const int ak = (tid & 3) << 2;
    const int bk = tid >> 4;
    const int bn4 = (tid & 15) << 2;
    float acc[4][4] = {};
    for (int k0 = 0; k0 < K; k0 += 16) {
        const U16x4 av = *(const U16x4*)(A + (size_t)(bm + ar) * K + k0 + ak);
        float4 af;
        af.x = bf2f(av.x); af.y = bf2f(av.y); af.z = bf2f(av.z); af.w = bf2f(av.w);
        *(float4*)&As[ar][ak] = af;
        *(float4*)&Bs[bk][bn4] = *(const float4*)(Bw + (size_t)(k0 + bk) * ldB + bn + bn4);
        __syncthreads();
        #pragma unroll
        for (int kk = 0; kk < 16; ++kk) {
            const float a0 = As[tr * 4 + 0][kk];
            const float a1 = As[tr * 4 + 1][kk];
            const float a2 = As[tr * 4 + 2][kk];
            const float a3 = As[tr * 4 + 3][kk];
            const float4 bv = *(const float4*)&Bs[kk][tc * 4];
            acc[0][0] += a0 * bv.x; acc[0][1] += a0 * bv.y; acc[0][2] += a0 * bv.z; acc[0][3] += a0 * bv.w;
            acc[1][0] += a1 * bv.x; acc[1][1] += a1 * bv.y; acc[1][2] += a1 * bv.z; acc[1][3] += a1 * bv.w;
            acc[2][0] += a2 * bv.x; acc[2][1] += a2 * bv.y; acc[2][2] += a2 * bv.z; acc[2][3] += a2 * bv.w;
            acc[3][0] += a3 * bv.x; acc[3][1] += a3 * bv.y; acc[3][2] += a3 * bv.z; acc[3][3] += a3 * bv.w;
        }
        __syncthreads();
    }
    const int col = bn + tc * 4;
    float4 bb = make_float4(0.f, 0.f, 0.f, 0.f);
    if (MODE != 4) bb = *(const float4*)(bias + col);
    #pragma unroll
    for (int i = 0; i < 4; ++i) {
        const int r = bm + tr * 4 + i;
        float4 v;
        v.x = acc[i][0] + bb.x; v.y = acc[i][1] + bb.y;
        v.z = acc[i][2] + bb.z; v.w = acc[i][3] + bb.w;
        if (MODE == 0) {
            U16x4 s = { f2bf(v.x), f2bf(v.y), f2bf(v.z), f2bf(v.w) };
            *(U16x4*)((u16*)outv + (size_t)r * Nn + col) = s;
        } else if (MODE == 1) {
            v.x = 0.5f * v.x * (1.0f + erff(v.x * 0.7071067811865476f));
            v.y = 0.5f * v.y * (1.0f + erff(v.y * 0.7071067811865476f));
            v.z = 0.5f * v.z * (1.0f + erff(v.z * 0.7071067811865476f));
            v.w = 0.5f * v.w * (1.0f + erff(v.w * 0.7071067811865476f));
            U16x4 s = { f2bf(v.x), f2bf(v.y), f2bf(v.z), f2bf(v.w) };
            *(U16x4*)((u16*)outv + (size_t)r * Nn + col) = s;
        } else if (MODE == 2) {
            const int win = r / kN, n = r % kN;
            const int b = win >> 6, wi = win & 63;
            const int wh = wi >> 3, ww = wi & 7;
            const int i1 = n / kWS, j1 = n % kWS;
            const int h = (wh * kWS + i1 + kSS) % kH;
            const int w = (ww * kWS + j1 + kSS) % kW;
            const size_t dest = ((size_t)b * kL + h * kW + w) * kC + col;
            const float4 xv = *(const float4*)(aux + dest);
            v.x += xv.x; v.y += xv.y; v.z += xv.z; v.w += xv.w;
            *(float4*)((float*)outv + dest) = v;
        } else if (MODE == 3) {
            const size_t off = (size_t)r * Nn + col;
            const float4 xv = *(const float4*)(aux + off);
            v.x += xv.x; v.y += xv.y; v.z += xv.z; v.w += xv.w;
            *(float4*)((float*)outv + off) = v;
        } else {  // MODE 4: accumulate
            const size_t off = (size_t)r * Nn + col;
            float* o = (float*)outv + off;
            const float4 cur = *(const float4*)o;
            v.x += cur.x; v.y += cur.y; v.z += cur.z; v.w += cur.w;
            *(float4*)o = v;
        }
    }
}

// ---------------------------------------------------------------------------
// Window attention: one block per (window, head). N=49, HD=32.
// qkv bf16 rows of 576 (q|k|v each 192 = head*32+d); out bf16 rows of 192.
// ---------------------------------------------------------------------------
__global__ __launch_bounds__(256) void attn_kernel(
    const u16* __restrict__ qkv, const float* __restrict__ btab,
    u16* __restrict__ out)
{
    __shared__ float Qs[49][33], Ks[49][33], Vs[49][33];
    __shared__ float Ss[49][50];
    const int win = blockIdx.x;
    const int head = blockIdx.y;
    const int tid = threadIdx.x;
    for (int idx = tid; idx < 49 * 32; idx += 256) {
        const int n = idx >> 5, d = idx & 31;
        const u16* p = qkv + (size_t)(win * 49 + n) * 576 + head * 32 + d;
        Qs[n][d] = bf2f(p[0]) * kScale;
        Ks[n][d] = bf2f(p[192]);
        Vs[n][d] = bf2f(p[384]);
    }
    __syncthreads();
    const int wi = win & 63;
    const int wh = wi >> 3, ww = wi & 7;
    for (int idx = tid; idx < 49 * 49; idx += 256) {
        const int n = idx / 49, m = idx - n * 49;
        float s = 0.f;
        #pragma unroll
        for (int d = 0; d < 32; ++d) s += Qs[n][d] * Ks[m][d];
        const int i1 = n / 7, j1 = n - i1 * 7;
        const int i2 = m / 7, j2 = m - i2 * 7;
        s += btab[((i1 - i2 + 6) * 13 + (j1 - j2 + 6)) * kNH + head];
        const int h1 = wh * 7 + i1, w1 = ww * 7 + j1;
        const int h2 = wh * 7 + i2, w2 = ww * 7 + j2;
        const int r1 = (h1 < 49 ? 0 : (h1 < 53 ? 1 : 2)) * 3 + (w1 < 49 ? 0 : (w1 < 53 ? 1 : 2));
        const int r2 = (h2 < 49 ? 0 : (h2 < 53 ? 1 : 2)) * 3 + (w2 < 49 ? 0 : (w2 < 53 ? 1 : 2));
        if (r1 != r2) s -= 100.0f;
        Ss[n][m] = s;
    }
    __syncthreads();
    if (tid < 49) {
        float mx = -1e30f;
        for (int m = 0; m < 49; ++m) mx = fmaxf(mx, Ss[tid][m]);
        float sum = 0.f;
        for (int m = 0; m < 49; ++m) { const float e = __expf(Ss[tid][m] - mx); Ss[tid][m] = e; sum += e; }
        const float inv = 1.0f / sum;
        for (int m = 0; m < 49; ++m) Ss[tid][m] *= inv;
    }
    __syncthreads();
    for (int idx = tid; idx < 49 * 32; idx += 256) {
        const int n = idx >> 5, d = idx & 31;
        float o = 0.f;
        #pragma unroll 7
        for (int m = 0; m < 49; ++m) o += Ss[n][m] * Vs[m][d];
        out[(size_t)(win * 49 + n) * 192 + head * 32 + d] = f2bf(o);
    }
}

// ---------------------------------------------------------------------------
extern "C" void kernel_launch(void* const* d_in, const int* in_sizes, int n_in,
                              void* d_out, int out_size, void* d_ws, size_t ws_size,
                              hipStream_t stream)
{
    const float* x      = (const float*)d_in[0];
    const float* gamma1 = (const float*)d_in[1];
    const float* beta1  = (const float*)d_in[2];
    const float* qkv_w  = (const float*)d_in[3];
    const float* qkv_b  = (const float*)d_in[4];
    const float* proj_w = (const float*)d_in[5];
    const float* proj_b = (const float*)d_in[6];
    const float* btab   = (const float*)d_in[7];
    const float* gamma2 = (const float*)d_in[8];
    const float* beta2  = (const float*)d_in[9];
    const float* fc1_w  = (const float*)d_in[10];
    const float* fc1_b  = (const float*)d_in[11];
    const float* fc2_w  = (const float*)d_in[12];
    const float* fc2_b  = (const float*)d_in[13];
    float* out = (float*)d_out;

    // Workspace (bf16): buf_a 192-wide (xw / attn_out / ynorm)   38.5 MB
    //                   buf_b 576-wide (qkv; mlp-half uses 384) 115.6 MB
    // x1 lives in d_out (fp32). Total d_ws use: 154.2 MB.
    u16* buf_a = (u16*)d_ws;                      // kTok*192 bf16
    u16* buf_b = buf_a + (size_t)kTok * 192;      // kTok*576 bf16

    // 1) LN1 + cyclic shift + window partition
    ln_kernel<<<kTok / 4, 256, 0, stream>>>(x, gamma1, beta1, buf_a, 1);
    // 2) qkv GEMM (100352 x 576 x 192), bf16 out
    gemm_k<0><<<dim3(9, kTok / 64), 256, 0, stream>>>(
        buf_a, qkv_w, 576, qkv_b, nullptr, buf_b, 576, 192);
    // 3) window attention -> buf_a (bf16)
    attn_kernel<<<dim3(kNWin, kNH), 256, 0, stream>>>(buf_b, btab, buf_a);
    // 4) proj GEMM + window reverse + unshift + residual(x) -> x1 in d_out
    gemm_k<2><<<dim3(3, kTok / 64), 256, 0, stream>>>(
        buf_a, proj_w, 192, proj_b, x, out, 192, 192);
    // 5) LN2 (reads x1 from d_out) -> buf_a (bf16)
    ln_kernel<<<kTok / 4, 256, 0, stream>>>(out, gamma2, beta2, buf_a, 0);
    // 6a) fc1 half 0 (cols 0..383) + GELU -> buf_b (bf16, 384-wide)
    gemm_k<1><<<dim3(6, kTok / 64), 256, 0, stream>>>(
        buf_a, fc1_w, 768, fc1_b, nullptr, buf_b, 384, 192);
    // 7a) fc2 half 0: d_out = hidden0 @ fc2_w[0:384] + bias + x1(d_out)
    gemm_k<3><<<dim3(3, kTok / 64), 256, 0, stream>>>(
        buf_b, fc2_w, 192, fc2_b, out, out, 192, 384);
    // 6b) fc1 half 1 (cols 384..767) + GELU -> buf_b
    gemm_k<1><<<dim3(6, kTok / 64), 256, 0, stream>>>(
        buf_a, fc1_w + 384, 768, fc1_b + 384, nullptr, buf_b, 384, 192);
    // 7b) fc2 half 1: d_out += hidden1 @ fc2_w[384:768]
    gemm_k<4><<<dim3(3, kTok / 64), 256, 0, stream>>>(
        buf_b, fc2_w + (size_t)384 * 192, 192, nullptr, nullptr, out, 192, 384);
}

// Round 3
// 969.555 us; speedup vs baseline: 1.7617x; 1.7617x over previous
//
#include <hip/hip_runtime.h>
#include <math.h>

namespace {
constexpr int kBatch = 32, kH = 56, kW = 56, kC = 192, kNH = 6, kWS = 7, kSS = 3;
constexpr int kL   = kH * kW;        // 3136
constexpr int kN   = kWS * kWS;      // 49
constexpr int kTok = kBatch * kL;    // 100352
constexpr int kNWin = kTok / kN;     // 2048 windows
constexpr float kEps   = 1e-3f;
constexpr float kScale = 0.17677669529663687f;  // HD^-0.5
}

typedef unsigned short u16;
typedef __attribute__((ext_vector_type(8))) short short8;   // 8 x bf16 (4 VGPRs)
typedef __attribute__((ext_vector_type(4))) float f32x4;    // MFMA accumulator

__device__ __forceinline__ float bf2f(u16 u) {
    return __uint_as_float(((unsigned int)u) << 16);
}
__device__ __forceinline__ u16 f2bf(float f) {  // round-to-nearest-even
    unsigned int x = __float_as_uint(f);
    return (u16)((x + 0x7FFFu + ((x >> 16) & 1u)) >> 16);
}

// ---------------------------------------------------------------------------
// LayerNorm over C=192 (fp32 in, bf16 out), one wave per token.
// do_shift=1: write into cyclic-shifted + window-partitioned layout.
// ---------------------------------------------------------------------------
__global__ __launch_bounds__(256) void ln_kernel(
    const float* __restrict__ x, const float* __restrict__ gamma,
    const float* __restrict__ beta, u16* __restrict__ out, int do_shift)
{
    const int wave = threadIdx.x >> 6;
    const int lane = threadIdx.x & 63;
    const int tok = (blockIdx.x << 2) + wave;
    const float* xp = x + (size_t)tok * kC;
    float v0 = xp[lane], v1 = xp[lane + 64], v2 = xp[lane + 128];
    float s  = v0 + v1 + v2;
    float sq = v0 * v0 + v1 * v1 + v2 * v2;
    #pragma unroll
    for (int off = 32; off > 0; off >>= 1) {
        s  += __shfl_down(s, off, 64);
        sq += __shfl_down(sq, off, 64);
    }
    s  = __shfl(s, 0, 64);
    sq = __shfl(sq, 0, 64);
    const float mean = s * (1.0f / kC);
    const float var  = sq * (1.0f / kC) - mean * mean;
    const float inv  = rsqrtf(var + kEps);
    size_t orow;
    if (do_shift) {
        const int b = tok / kL, hw = tok % kL;
        const int h = hw / kW, w = hw % kW;
        const int hs = (h + kH - kSS) % kH;
        const int ws = (w + kW - kSS) % kW;
        const int wh = hs / kWS, ii = hs % kWS;
        const int ww = ws / kWS, jj = ws % kWS;
        orow = (size_t)(b * 64 + wh * 8 + ww) * kN + (ii * kWS + jj);
    } else {
        orow = tok;
    }
    u16* op = out + orow * kC;
    op[lane]       = f2bf((v0 - mean) * inv * gamma[lane]       + beta[lane]);
    op[lane + 64]  = f2bf((v1 - mean) * inv * gamma[lane + 64]  + beta[lane + 64]);
    op[lane + 128] = f2bf((v2 - mean) * inv * gamma[lane + 128] + beta[lane + 128]);
}

// ---------------------------------------------------------------------------
// Weight prep: fp32 K x Nn (k-major) -> bf16 Nn x K (n-major) for MFMA B-frags.
// ---------------------------------------------------------------------------
__global__ __launch_bounds__(256) void wprep_qkv(
    const float* __restrict__ w, u16* __restrict__ wt)
{
    const int idx = blockIdx.x * 256 + threadIdx.x;   // 576*192 = 110592
    if (idx >= 576 * 192) return;
    const int n = idx / 192, k = idx - n * 192;
    wt[idx] = f2bf(w[(size_t)k * 576 + n]);
}

__global__ __launch_bounds__(256) void wprep_rest(
    const float* __restrict__ pw, const float* __restrict__ f1w,
    const float* __restrict__ f2w, u16* __restrict__ proj_t,
    u16* __restrict__ f1_t, u16* __restrict__ f2_t)
{
    int idx = blockIdx.x * 256 + threadIdx.x;
    if (idx < 36864) {                       // proj: 192 x 192
        const int n = idx / 192, k = idx - n * 192;
        proj_t[idx] = f2bf(pw[(size_t)k * 192 + n]);
        return;
    }
    idx -= 36864;
    if (idx < 147456) {                      // fc1: Bt 768 x 192
        const int n = idx / 192, k = idx - n * 192;
        f1_t[idx] = f2bf(f1w[(size_t)k * 768 + n]);
        return;
    }
    idx -= 147456;
    if (idx < 147456) {                      // fc2: Bt 192 x 768
        const int n = idx / 768, k = idx - n * 768;
        f2_t[idx] = f2bf(f2w[(size_t)k * 192 + n]);
    }
}

// ---------------------------------------------------------------------------
// MFMA GEMM: out(M x Nn) = A_bf16(M x K) @ B + bias.  Bt is bf16, n-major
// (row n holds K contiguous k's, row stride ldb).  Block = 64 rows x 192
// cols (NJ j-tiles of 192), 4 waves; wave w covers cols w*48..w*48+48 as
// 4 m-frags x 3 n-frags of 16x16x32 MFMA. No LDS: A-frag loads are 16 rows
// x 64B coalesced; Bt is L2-resident (<=0.3 MB per GEMM).
// MODE 0: bf16 out   1: GELU bf16 out   2: scatter+residual(aux) fp32 out
// MODE 3: +bias +aux fp32 out           4: accumulate into fp32 out
// ---------------------------------------------------------------------------
template <int MODE, int K, int NJ>
__global__ __launch_bounds__(256) void gemm_mfma(
    const u16* __restrict__ A, const u16* __restrict__ Bt, int ldb,
    const float* __restrict__ bias, const float* __restrict__ aux,
    void* __restrict__ outv)
{
    constexpr int Nn = NJ * 192;
    const int tid  = threadIdx.x;
    const int wave = tid >> 6, lane = tid & 63;
    const int quad = lane >> 4, l15 = lane & 15;
    const int m0 = blockIdx.x * 64;

    const u16* Abase = A + (size_t)(m0 + l15) * K + quad * 8;

    #pragma unroll
    for (int j = 0; j < NJ; ++j) {
        const int nb0 = j * 192 + wave * 48;
        const u16* Bbase = Bt + (size_t)(nb0 + l15) * ldb + quad * 8;
        f32x4 acc[4][3] = {};
        #pragma unroll
        for (int ks = 0; ks < K / 32; ++ks) {
            short8 a[4], b[3];
            #pragma unroll
            for (int i = 0; i < 4; ++i)
                a[i] = *(const short8*)(Abase + (size_t)i * 16 * K + ks * 32);
            #pragma unroll
            for (int t = 0; t < 3; ++t)
                b[t] = *(const short8*)(Bbase + (size_t)t * 16 * ldb + ks * 32);
            #pragma unroll
            for (int i = 0; i < 4; ++i)
                #pragma unroll
                for (int t = 0; t < 3; ++t)
                    acc[i][t] = __builtin_amdgcn_mfma_f32_16x16x32_bf16(
                        a[i], b[t], acc[i][t], 0, 0, 0);
        }
        // ---- epilogue: row r = m0+i*16+quad*4+reg, col c = nb0+t*16+l15 ----
        float bcol[3] = {0.f, 0.f, 0.f};
        if (MODE != 4) {
            #pragma unroll
            for (int t = 0; t < 3; ++t) bcol[t] = bias[nb0 + t * 16 + l15];
        }
        #pragma unroll
        for (int i = 0; i < 4; ++i) {
            #pragma unroll
            for (int reg = 0; reg < 4; ++reg) {
                const int r = m0 + i * 16 + quad * 4 + reg;
                if (MODE == 2) {
                    const int win = r / kN, n = r % kN;
                    const int b = win >> 6, wi = win & 63;
                    const int wh = wi >> 3, ww = wi & 7;
                    const int i1 = n / kWS, j1 = n % kWS;
                    const int h = (wh * kWS + i1 + kSS) % kH;
                    const int w = (ww * kWS + j1 + kSS) % kW;
                    const size_t drow = ((size_t)b * kL + h * kW + w) * kC;
                    #pragma unroll
                    for (int t = 0; t < 3; ++t) {
                        const int c = nb0 + t * 16 + l15;
                        const size_t dest = drow + c;
                        ((float*)outv)[dest] = acc[i][t][reg] + bcol[t] + aux[dest];
                    }
                } else if (MODE == 3) {
                    #pragma unroll
                    for (int t = 0; t < 3; ++t) {
                        const int c = nb0 + t * 16 + l15;
                        const size_t off = (size_t)r * Nn + c;
                        ((float*)outv)[off] = acc[i][t][reg] + bcol[t] + aux[off];
                    }
                } else if (MODE == 4) {
                    #pragma unroll
                    for (int t = 0; t < 3; ++t) {
                        const int c = nb0 + t * 16 + l15;
                        const size_t off = (size_t)r * Nn + c;
                        ((float*)outv)[off] += acc[i][t][reg];
                    }
                } else {
                    #pragma unroll
                    for (int t = 0; t < 3; ++t) {
                        const int c = nb0 + t * 16 + l15;
                        float v = acc[i][t][reg] + bcol[t];
                        if (MODE == 1)
                            v = 0.5f * v * (1.0f + erff(v * 0.7071067811865476f));
                        ((u16*)outv)[(size_t)r * Nn + c] = f2bf(v);
                    }
                }
            }
        }
    }
}

// ---------------------------------------------------------------------------
// Window attention: one block per (window, head). N=49, HD=32.
// ---------------------------------------------------------------------------
__global__ __launch_bounds__(256) void attn_kernel(
    const u16* __restrict__ qkv, const float* __restrict__ btab,
    u16* __restrict__ out)
{
    __shared__ float Qs[49][33], Ks[49][33], Vs[49][33];
    __shared__ float Ss[49][50];
    const int win = blockIdx.x;
    const int head = blockIdx.y;
    const int tid = threadIdx.x;
    for (int idx = tid; idx < 49 * 32; idx += 256) {
        const int n = idx >> 5, d = idx & 31;
        const u16* p = qkv + (size_t)(win * 49 + n) * 576 + head * 32 + d;
        Qs[n][d] = bf2f(p[0]) * kScale;
        Ks[n][d] = bf2f(p[192]);
        Vs[n][d] = bf2f(p[384]);
    }
    __syncthreads();
    const int wi = win & 63;
    const int wh = wi >> 3, ww = wi & 7;
    for (int idx = tid; idx < 49 * 49; idx += 256) {
        const int n = idx / 49, m = idx - n * 49;
        float s = 0.f;
        #pragma unroll
        for (int d = 0; d < 32; ++d) s += Qs[n][d] * Ks[m][d];
        const int i1 = n / 7, j1 = n - i1 * 7;
        const int i2 = m / 7, j2 = m - i2 * 7;
        s += btab[((i1 - i2 + 6) * 13 + (j1 - j2 + 6)) * kNH + head];
        const int h1 = wh * 7 + i1, w1 = ww * 7 + j1;
        const int h2 = wh * 7 + i2, w2 = ww * 7 + j2;
        const int r1 = (h1 < 49 ? 0 : (h1 < 53 ? 1 : 2)) * 3 + (w1 < 49 ? 0 : (w1 < 53 ? 1 : 2));
        const int r2 = (h2 < 49 ? 0 : (h2 < 53 ? 1 : 2)) * 3 + (w2 < 49 ? 0 : (w2 < 53 ? 1 : 2));
        if (r1 != r2) s -= 100.0f;
        Ss[n][m] = s;
    }
    __syncthreads();
    if (tid < 49) {
        float mx = -1e30f;
        for (int m = 0; m < 49; ++m) mx = fmaxf(mx, Ss[tid][m]);
        float sum = 0.f;
        for (int m = 0; m < 49; ++m) { const float e = __expf(Ss[tid][m] - mx); Ss[tid][m] = e; sum += e; }
        const float inv = 1.0f / sum;
        for (int m = 0; m < 49; ++m) Ss[tid][m] *= inv;
    }
    __syncthreads();
    for (int idx = tid; idx < 49 * 32; idx += 256) {
        const int n = idx >> 5, d = idx & 31;
        float o = 0.f;
        #pragma unroll 7
        for (int m = 0; m < 49; ++m) o += Ss[n][m] * Vs[m][d];
        out[(size_t)(win * 49 + n) * 192 + head * 32 + d] = f2bf(o);
    }
}

// ---------------------------------------------------------------------------
extern "C" void kernel_launch(void* const* d_in, const int* in_sizes, int n_in,
                              void* d_out, int out_size, void* d_ws, size_t ws_size,
                              hipStream_t stream)
{
    const float* x      = (const float*)d_in[0];
    const float* gamma1 = (const float*)d_in[1];
    const float* beta1  = (const float*)d_in[2];
    const float* qkv_w  = (const float*)d_in[3];
    const float* qkv_b  = (const float*)d_in[4];
    const float* proj_w = (const float*)d_in[5];
    const float* proj_b = (const float*)d_in[6];
    const float* btab   = (const float*)d_in[7];
    const float* gamma2 = (const float*)d_in[8];
    const float* beta2  = (const float*)d_in[9];
    const float* fc1_w  = (const float*)d_in[10];
    const float* fc1_b  = (const float*)d_in[11];
    const float* fc2_w  = (const float*)d_in[12];
    const float* fc2_b  = (const float*)d_in[13];
    float* out = (float*)d_out;

    // ws budget is EXACTLY kTok*768*2 B (== 2x out bytes) — round 1 proved
    // overshoot aborts. buf_a: kTok*192 bf16; buf_b: kTok*576 bf16.
    // bf16 n-major weights live in dead regions:
    //   qkv_wt -> start of d_out (dead until proj epilogue overwrites it)
    //   proj/fc1/fc2_wt -> tail of buf_b, written AFTER attn consumed qkv.
    u16* buf_a = (u16*)d_ws;                      // kTok*192
    u16* buf_b = buf_a + (size_t)kTok * 192;      // kTok*576 (qkv / mlp hidden 384)
    u16* qkv_t = (u16*)d_out;                     // 110592 elems scratch
    u16* wt2   = (u16*)d_ws + (size_t)kTok * 768 - 331776;  // tail of buf_b
    u16* proj_t = wt2;                            // 36864
    u16* f1_t   = wt2 + 36864;                    // 147456 (768 x 192)
    u16* f2_t   = f1_t + 147456;                  // 147456 (192 x 768)

    // 0) qkv weight prep (into d_out scratch)
    wprep_qkv<<<(110592 + 255) / 256, 256, 0, stream>>>(qkv_w, qkv_t);
    // 1) LN1 + cyclic shift + window partition
    ln_kernel<<<kTok / 4, 256, 0, stream>>>(x, gamma1, beta1, buf_a, 1);
    // 2) qkv GEMM (100352 x 576 x 192) -> buf_b (bf16)
    gemm_mfma<0, 192, 3><<<kTok / 64, 256, 0, stream>>>(
        buf_a, qkv_t, 192, qkv_b, nullptr, buf_b);
    // 3) window attention -> buf_a (bf16); frees buf_b and d_out scratch
    attn_kernel<<<dim3(kNWin, kNH), 256, 0, stream>>>(buf_b, btab, buf_a);
    // 4) remaining weight prep into buf_b tail (qkv dead now)
    wprep_rest<<<(331776 + 255) / 256, 256, 0, stream>>>(
        proj_w, fc1_w, fc2_w, proj_t, f1_t, f2_t);
    // 5) proj GEMM + window reverse + unshift + residual(x) -> x1 in d_out
    gemm_mfma<2, 192, 1><<<kTok / 64, 256, 0, stream>>>(
        buf_a, proj_t, 192, proj_b, x, out);
    // 6) LN2 (x1 in d_out) -> buf_a
    ln_kernel<<<kTok / 4, 256, 0, stream>>>(out, gamma2, beta2, buf_a, 0);
    // 7a) fc1 half 0 + GELU -> hidden (buf_b start, 384-wide bf16)
    gemm_mfma<1, 192, 2><<<kTok / 64, 256, 0, stream>>>(
        buf_a, f1_t, 192, fc1_b, nullptr, buf_b);
    // 8a) fc2 half 0: out = hidden0 @ fc2[0:384] + bias + x1
    gemm_mfma<3, 384, 1><<<kTok / 64, 256, 0, stream>>>(
        buf_b, f2_t, 768, fc2_b, out, out);
    // 7b) fc1 half 1 + GELU -> hidden
    gemm_mfma<1, 192, 2><<<kTok / 64, 256, 0, stream>>>(
        buf_a, f1_t + (size_t)384 * 192, 192, fc1_b + 384, nullptr, buf_b);
    // 8b) fc2 half 1: out += hidden1 @ fc2[384:768]
    gemm_mfma<4, 384, 1><<<kTok / 64, 256, 0, stream>>>(
        buf_b, f2_t + 384, 768, nullptr, nullptr, out);
}

// Round 4
// 793.935 us; speedup vs baseline: 2.1514x; 1.2212x over previous
//
#include <hip/hip_runtime.h>
#include <math.h>

namespace {
constexpr int kBatch = 32, kH = 56, kW = 56, kC = 192, kNH = 6, kWS = 7, kSS = 3;
constexpr int kL   = kH * kW;        // 3136
constexpr int kN   = kWS * kWS;      // 49
constexpr int kTok = kBatch * kL;    // 100352
constexpr int kNWin = kTok / kN;     // 2048 windows
constexpr float kEps   = 1e-3f;
constexpr float kScale = 0.17677669529663687f;  // HD^-0.5
}

typedef unsigned short u16;
typedef __attribute__((ext_vector_type(8))) short short8;   // 8 x bf16 (4 VGPRs)
typedef __attribute__((ext_vector_type(4))) float f32x4;    // MFMA accumulator

__device__ __forceinline__ float bf2f(u16 u) {
    return __uint_as_float(((unsigned int)u) << 16);
}
__device__ __forceinline__ u16 f2bf(float f) {  // round-to-nearest-even
    unsigned int x = __float_as_uint(f);
    return (u16)((x + 0x7FFFu + ((x >> 16) & 1u)) >> 16);
}

// ---------------------------------------------------------------------------
// LayerNorm over C=192 (fp32 in, bf16 out), one wave per token.
// ---------------------------------------------------------------------------
__global__ __launch_bounds__(256) void ln_kernel(
    const float* __restrict__ x, const float* __restrict__ gamma,
    const float* __restrict__ beta, u16* __restrict__ out, int do_shift)
{
    const int wave = threadIdx.x >> 6;
    const int lane = threadIdx.x & 63;
    const int tok = (blockIdx.x << 2) + wave;
    const float* xp = x + (size_t)tok * kC;
    float v0 = xp[lane], v1 = xp[lane + 64], v2 = xp[lane + 128];
    float s  = v0 + v1 + v2;
    float sq = v0 * v0 + v1 * v1 + v2 * v2;
    #pragma unroll
    for (int off = 32; off > 0; off >>= 1) {
        s  += __shfl_down(s, off, 64);
        sq += __shfl_down(sq, off, 64);
    }
    s  = __shfl(s, 0, 64);
    sq = __shfl(sq, 0, 64);
    const float mean = s * (1.0f / kC);
    const float var  = sq * (1.0f / kC) - mean * mean;
    const float inv  = rsqrtf(var + kEps);
    size_t orow;
    if (do_shift) {
        const int b = tok / kL, hw = tok % kL;
        const int h = hw / kW, w = hw % kW;
        const int hs = (h + kH - kSS) % kH;
        const int ws = (w + kW - kSS) % kW;
        const int wh = hs / kWS, ii = hs % kWS;
        const int ww = ws / kWS, jj = ws % kWS;
        orow = (size_t)(b * 64 + wh * 8 + ww) * kN + (ii * kWS + jj);
    } else {
        orow = tok;
    }
    u16* op = out + orow * kC;
    op[lane]       = f2bf((v0 - mean) * inv * gamma[lane]       + beta[lane]);
    op[lane + 64]  = f2bf((v1 - mean) * inv * gamma[lane + 64]  + beta[lane + 64]);
    op[lane + 128] = f2bf((v2 - mean) * inv * gamma[lane + 128] + beta[lane + 128]);
}

// ---------------------------------------------------------------------------
// Weight prep: fp32 K x Nn (k-major) -> bf16 Nn x K (n-major).
// ---------------------------------------------------------------------------
__global__ __launch_bounds__(256) void wprep_qkv(
    const float* __restrict__ w, u16* __restrict__ wt)
{
    const int idx = blockIdx.x * 256 + threadIdx.x;
    if (idx >= 576 * 192) return;
    const int n = idx / 192, k = idx - n * 192;
    wt[idx] = f2bf(w[(size_t)k * 576 + n]);
}

__global__ __launch_bounds__(256) void wprep_rest(
    const float* __restrict__ pw, const float* __restrict__ f1w,
    const float* __restrict__ f2w, u16* __restrict__ proj_t,
    u16* __restrict__ f1_t, u16* __restrict__ f2_t)
{
    int idx = blockIdx.x * 256 + threadIdx.x;
    if (idx < 36864) {
        const int n = idx / 192, k = idx - n * 192;
        proj_t[idx] = f2bf(pw[(size_t)k * 192 + n]);
        return;
    }
    idx -= 36864;
    if (idx < 147456) {
        const int n = idx / 192, k = idx - n * 192;
        f1_t[idx] = f2bf(f1w[(size_t)k * 768 + n]);
        return;
    }
    idx -= 147456;
    if (idx < 147456) {
        const int n = idx / 768, k = idx - n * 768;
        f2_t[idx] = f2bf(f2w[(size_t)k * 192 + n]);
    }
}

// ---------------------------------------------------------------------------
// Bias+mask table: T[cls][head][n][m], cls = (whEdge<<1)|wwEdge.
// ---------------------------------------------------------------------------
__global__ __launch_bounds__(256) void prep_bm(
    const float* __restrict__ btab, float* __restrict__ T)
{
    const int idx = blockIdx.x * 256 + threadIdx.x;
    if (idx >= 4 * 6 * 49 * 49) return;
    const int m = idx % 49, n = (idx / 49) % 49;
    const int head = (idx / 2401) % 6, cls = idx / (2401 * 6);
    const int i1 = n / 7, j1 = n % 7, i2 = m / 7, j2 = m % 7;
    float v = btab[((i1 - i2 + 6) * 13 + (j1 - j2 + 6)) * kNH + head];
    const int whE = cls >> 1, wwE = cls & 1;
    const int r1 = (whE ? (i1 < 4 ? 1 : 2) : 0) * 3 + (wwE ? (j1 < 4 ? 1 : 2) : 0);
    const int r2 = (whE ? (i2 < 4 ? 1 : 2) : 0) * 3 + (wwE ? (j2 < 4 ? 1 : 2) : 0);
    if (r1 != r2) v -= 100.f;
    T[idx] = v;
}

// ---------------------------------------------------------------------------
// MFMA GEMM (unchanged from round 3).
// ---------------------------------------------------------------------------
template <int MODE, int K, int NJ>
__global__ __launch_bounds__(256) void gemm_mfma(
    const u16* __restrict__ A, const u16* __restrict__ Bt, int ldb,
    const float* __restrict__ bias, const float* __restrict__ aux,
    void* __restrict__ outv)
{
    constexpr int Nn = NJ * 192;
    const int tid  = threadIdx.x;
    const int wave = tid >> 6, lane = tid & 63;
    const int quad = lane >> 4, l15 = lane & 15;
    const int m0 = blockIdx.x * 64;

    const u16* Abase = A + (size_t)(m0 + l15) * K + quad * 8;

    #pragma unroll
    for (int j = 0; j < NJ; ++j) {
        const int nb0 = j * 192 + wave * 48;
        const u16* Bbase = Bt + (size_t)(nb0 + l15) * ldb + quad * 8;
        f32x4 acc[4][3] = {};
        #pragma unroll
        for (int ks = 0; ks < K / 32; ++ks) {
            short8 a[4], b[3];
            #pragma unroll
            for (int i = 0; i < 4; ++i)
                a[i] = *(const short8*)(Abase + (size_t)i * 16 * K + ks * 32);
            #pragma unroll
            for (int t = 0; t < 3; ++t)
                b[t] = *(const short8*)(Bbase + (size_t)t * 16 * ldb + ks * 32);
            #pragma unroll
            for (int i = 0; i < 4; ++i)
                #pragma unroll
                for (int t = 0; t < 3; ++t)
                    acc[i][t] = __builtin_amdgcn_mfma_f32_16x16x32_bf16(
                        a[i], b[t], acc[i][t], 0, 0, 0);
        }
        float bcol[3] = {0.f, 0.f, 0.f};
        if (MODE != 4) {
            #pragma unroll
            for (int t = 0; t < 3; ++t) bcol[t] = bias[nb0 + t * 16 + l15];
        }
        #pragma unroll
        for (int i = 0; i < 4; ++i) {
            #pragma unroll
            for (int reg = 0; reg < 4; ++reg) {
                const int r = m0 + i * 16 + quad * 4 + reg;
                if (MODE == 2) {
                    const int win = r / kN, n = r % kN;
                    const int b = win >> 6, wi = win & 63;
                    const int wh = wi >> 3, ww = wi & 7;
                    const int i1 = n / kWS, j1 = n % kWS;
                    const int h = (wh * kWS + i1 + kSS) % kH;
                    const int w = (ww * kWS + j1 + kSS) % kW;
                    const size_t drow = ((size_t)b * kL + h * kW + w) * kC;
                    #pragma unroll
                    for (int t = 0; t < 3; ++t) {
                        const int c = nb0 + t * 16 + l15;
                        const size_t dest = drow + c;
                        ((float*)outv)[dest] = acc[i][t][reg] + bcol[t] + aux[dest];
                    }
                } else if (MODE == 3) {
                    #pragma unroll
                    for (int t = 0; t < 3; ++t) {
                        const int c = nb0 + t * 16 + l15;
                        const size_t off = (size_t)r * Nn + c;
                        ((float*)outv)[off] = acc[i][t][reg] + bcol[t] + aux[off];
                    }
                } else if (MODE == 4) {
                    #pragma unroll
                    for (int t = 0; t < 3; ++t) {
                        const int c = nb0 + t * 16 + l15;
                        const size_t off = (size_t)r * Nn + c;
                        ((float*)outv)[off] += acc[i][t][reg];
                    }
                } else {
                    #pragma unroll
                    for (int t = 0; t < 3; ++t) {
                        const int c = nb0 + t * 16 + l15;
                        float v = acc[i][t][reg] + bcol[t];
                        if (MODE == 1)
                            v = 0.5f * v * (1.0f + erff(v * 0.7071067811865476f));
                        ((u16*)outv)[(size_t)r * Nn + c] = f2bf(v);
                    }
                }
            }
        }
    }
}

// ---------------------------------------------------------------------------
// MFMA window attention: ONE WAVE per (window, head). N=49 padded to 64,
// HD=32. S=QK^T: A=Q rows, B=K rows, direct 16B/lane global frag loads,
// single k-step. Register softmax (rows span the 16 lanes of a quad;
// normalization deferred to epilogue). P->LDS bf16 (stride 72), V->LDS
// transposed, PV: 16 MFMAs. Wave-private LDS => no barriers.
// ---------------------------------------------------------------------------
__global__ __launch_bounds__(256) void attn_mfma(
    const u16* __restrict__ qkv, const float* __restrict__ T,
    u16* __restrict__ out)
{
    __shared__ u16 Ps[4][64][72];
    __shared__ u16 Vt[4][32][72];
    const int tid = threadIdx.x;
    const int wave = tid >> 6, lane = tid & 63;
    const int quad = lane >> 4, l15 = lane & 15;
    const int pair = blockIdx.x * 4 + wave;
    const int win = pair / 6, head = pair - win * 6;
    const int wi = win & 63;
    const int cls = (((wi >> 3) == 7) ? 2 : 0) + (((wi & 7) == 7) ? 1 : 0);
    const float* Tb = T + (size_t)(cls * 6 + head) * 49 * 49;

    // --- load Q,K fragments (A[m=l15][k=quad*8+j], B mirrored) ---
    const u16* base = qkv + (size_t)win * 49 * 576 + head * 32 + quad * 8;
    short8 zz = {};
    short8 qa[4], kb[4];
    #pragma unroll
    for (int i = 0; i < 4; ++i) {
        const int n = i * 16 + l15;
        qa[i] = (n < 49) ? *(const short8*)(base + (size_t)n * 576) : zz;
        kb[i] = (n < 49) ? *(const short8*)(base + (size_t)n * 576 + 192) : zz;
    }
    // --- V -> Vt transposed; zero pad columns 49..63 ---
    for (int z = lane; z < 32 * 16; z += 64)
        if (z & 15) Vt[wave][z >> 4][48 + (z & 15)] = 0;
    const u16* vbase = qkv + (size_t)win * 49 * 576 + 384 + head * 32;
    for (int idx = lane; idx < 49 * 16; idx += 64) {
        const int n = idx >> 4, dp = (idx & 15) << 1;
        const u16* p = vbase + (size_t)n * 576 + dp;
        Vt[wave][dp][n]     = p[0];
        Vt[wave][dp + 1][n] = p[1];
    }
    // --- S = Q @ K^T (16 MFMAs, one k-step) ---
    f32x4 acc[4][4] = {};
    #pragma unroll
    for (int i = 0; i < 4; ++i)
        #pragma unroll
        for (int j = 0; j < 4; ++j)
            acc[i][j] = __builtin_amdgcn_mfma_f32_16x16x32_bf16(
                qa[i], kb[j], acc[i][j], 0, 0, 0);
    // --- softmax over rows (row n -> lanes of one quad), store P to LDS ---
    float rowinv[4][4];
    #pragma unroll
    for (int i = 0; i < 4; ++i) {
        #pragma unroll
        for (int reg = 0; reg < 4; ++reg) {
            const int n = i * 16 + quad * 4 + reg;
            const int nc = (n < 49) ? n : 48;
            float s[4];
            #pragma unroll
            for (int j = 0; j < 4; ++j) {
                const int m = j * 16 + l15;
                s[j] = (m < 49) ? fmaf(acc[i][j][reg], kScale, Tb[nc * 49 + m])
                                : -1e30f;
            }
            float mx = fmaxf(fmaxf(s[0], s[1]), fmaxf(s[2], s[3]));
            #pragma unroll
            for (int off = 1; off < 16; off <<= 1)
                mx = fmaxf(mx, __shfl_xor(mx, off, 64));
            float e0 = __expf(s[0] - mx), e1 = __expf(s[1] - mx);
            float e2 = __expf(s[2] - mx), e3 = __expf(s[3] - mx);
            float sum = e0 + e1 + e2 + e3;
            #pragma unroll
            for (int off = 1; off < 16; off <<= 1)
                sum += __shfl_xor(sum, off, 64);
            rowinv[i][reg] = 1.0f / sum;
            Ps[wave][n][0 * 16 + l15] = f2bf(e0);
            Ps[wave][n][1 * 16 + l15] = f2bf(e1);
            Ps[wave][n][2 * 16 + l15] = f2bf(e2);
            Ps[wave][n][3 * 16 + l15] = f2bf(e3);
        }
    }
    // --- O = P @ V (16 MFMAs over 2 k-steps) ---
    f32x4 o[4][2] = {};
    #pragma unroll
    for (int ks = 0; ks < 2; ++ks) {
        short8 pa[4], vb[2];
        #pragma unroll
        for (int i = 0; i < 4; ++i)
            pa[i] = *(const short8*)&Ps[wave][i * 16 + l15][ks * 32 + quad * 8];
        #pragma unroll
        for (int t = 0; t < 2; ++t)
            vb[t] = *(const short8*)&Vt[wave][t * 16 + l15][ks * 32 + quad * 8];
        #pragma unroll
        for (int i = 0; i < 4; ++i)
            #pragma unroll
            for (int t = 0; t < 2; ++t)
                o[i][t] = __builtin_amdgcn_mfma_f32_16x16x32_bf16(
                    pa[i], vb[t], o[i][t], 0, 0, 0);
    }
    // --- epilogue: normalize, write rows n<49 ---
    u16* obase = out + (size_t)win * 49 * 192 + head * 32;
    #pragma unroll
    for (int i = 0; i < 4; ++i) {
        #pragma unroll
        for (int reg = 0; reg < 4; ++reg) {
            const int n = i * 16 + quad * 4 + reg;
            if (n < 49) {
                const float inv = rowinv[i][reg];
                obase[(size_t)n * 192 + l15]      = f2bf(o[i][0][reg] * inv);
                obase[(size_t)n * 192 + 16 + l15] = f2bf(o[i][1][reg] * inv);
            }
        }
    }
}

// ---------------------------------------------------------------------------
extern "C" void kernel_launch(void* const* d_in, const int* in_sizes, int n_in,
                              void* d_out, int out_size, void* d_ws, size_t ws_size,
                              hipStream_t stream)
{
    const float* x      = (const float*)d_in[0];
    const float* gamma1 = (const float*)d_in[1];
    const float* beta1  = (const float*)d_in[2];
    const float* qkv_w  = (const float*)d_in[3];
    const float* qkv_b  = (const float*)d_in[4];
    const float* proj_w = (const float*)d_in[5];
    const float* proj_b = (const float*)d_in[6];
    const float* btab   = (const float*)d_in[7];
    const float* gamma2 = (const float*)d_in[8];
    const float* beta2  = (const float*)d_in[9];
    const float* fc1_w  = (const float*)d_in[10];
    const float* fc1_b  = (const float*)d_in[11];
    const float* fc2_w  = (const float*)d_in[12];
    const float* fc2_b  = (const float*)d_in[13];
    float* out = (float*)d_out;

    // ws budget EXACTLY kTok*768*2 B. Scratch in dead regions:
    //   qkv_t + bm table -> start of d_out (dead until proj epilogue)
    //   proj/fc1/fc2 bf16 weights -> tail of buf_b (written after attn)
    u16* buf_a = (u16*)d_ws;                      // kTok*192 bf16
    u16* buf_b = buf_a + (size_t)kTok * 192;      // kTok*576 bf16
    u16* qkv_t = (u16*)d_out;                     // 110592 u16
    float* bm_tab = (float*)d_out + 55296;        // 57624 floats (after qkv_t)
    u16* wt2   = (u16*)d_ws + (size_t)kTok * 768 - 331776;
    u16* proj_t = wt2;
    u16* f1_t   = wt2 + 36864;
    u16* f2_t   = f1_t + 147456;

    // 0) weight + bias/mask table prep (into d_out scratch)
    wprep_qkv<<<(110592 + 255) / 256, 256, 0, stream>>>(qkv_w, qkv_t);
    prep_bm<<<(57624 + 255) / 256, 256, 0, stream>>>(btab, bm_tab);
    // 1) LN1 + cyclic shift + window partition
    ln_kernel<<<kTok / 4, 256, 0, stream>>>(x, gamma1, beta1, buf_a, 1);
    // 2) qkv GEMM -> buf_b (bf16)
    gemm_mfma<0, 192, 3><<<kTok / 64, 256, 0, stream>>>(
        buf_a, qkv_t, 192, qkv_b, nullptr, buf_b);
    // 3) MFMA window attention -> buf_a (bf16)
    attn_mfma<<<(kNWin * kNH) / 4, 256, 0, stream>>>(buf_b, bm_tab, buf_a);
    // 4) remaining weight prep into buf_b tail (qkv dead now)
    wprep_rest<<<(331776 + 255) / 256, 256, 0, stream>>>(
        proj_w, fc1_w, fc2_w, proj_t, f1_t, f2_t);
    // 5) proj GEMM + window reverse + unshift + residual(x) -> x1 in d_out
    gemm_mfma<2, 192, 1><<<kTok / 64, 256, 0, stream>>>(
        buf_a, proj_t, 192, proj_b, x, out);
    // 6) LN2 -> buf_a
    ln_kernel<<<kTok / 4, 256, 0, stream>>>(out, gamma2, beta2, buf_a, 0);
    // 7a) fc1 half 0 + GELU -> buf_b (384-wide bf16)
    gemm_mfma<1, 192, 2><<<kTok / 64, 256, 0, stream>>>(
        buf_a, f1_t, 192, fc1_b, nullptr, buf_b);
    // 8a) fc2 half 0: out = hidden0 @ fc2[0:384] + bias + x1
    gemm_mfma<3, 384, 1><<<kTok / 64, 256, 0, stream>>>(
        buf_b, f2_t, 768, fc2_b, out, out);
    // 7b) fc1 half 1 + GELU -> buf_b
    gemm_mfma<1, 192, 2><<<kTok / 64, 256, 0, stream>>>(
        buf_a, f1_t + (size_t)384 * 192, 192, fc1_b + 384, nullptr, buf_b);
    // 8b) fc2 half 1: out += hidden1 @ fc2[384:768]
    gemm_mfma<4, 384, 1><<<kTok / 64, 256, 0, stream>>>(
        buf_b, f2_t + 384, 768, nullptr, nullptr, out);
}

// Round 5
// 701.625 us; speedup vs baseline: 2.4345x; 1.1316x over previous
//
#include <hip/hip_runtime.h>
#include <math.h>

namespace {
constexpr int kBatch = 32, kH = 56, kW = 56, kC = 192, kNH = 6, kWS = 7, kSS = 3;
constexpr int kL   = kH * kW;        // 3136
constexpr int kN   = kWS * kWS;      // 49
constexpr int kTok = kBatch * kL;    // 100352
constexpr int kNWin = kTok / kN;     // 2048 windows
constexpr float kEps   = 1e-3f;
constexpr float kScale = 0.17677669529663687f;  // HD^-0.5
}

typedef unsigned short u16;
typedef __attribute__((ext_vector_type(8))) short short8;   // 8 x bf16 (4 VGPRs)
typedef __attribute__((ext_vector_type(4))) float f32x4;    // MFMA accumulator

__device__ __forceinline__ float bf2f(u16 u) {
    return __uint_as_float(((unsigned int)u) << 16);
}
__device__ __forceinline__ u16 f2bf(float f) {  // round-to-nearest-even
    unsigned int x = __float_as_uint(f);
    return (u16)((x + 0x7FFFu + ((x >> 16) & 1u)) >> 16);
}

// ---------------------------------------------------------------------------
// LayerNorm over C=192 (fp32 in, bf16 out), one wave per token.
// ---------------------------------------------------------------------------
__global__ __launch_bounds__(256) void ln_kernel(
    const float* __restrict__ x, const float* __restrict__ gamma,
    const float* __restrict__ beta, u16* __restrict__ out, int do_shift)
{
    const int wave = threadIdx.x >> 6;
    const int lane = threadIdx.x & 63;
    const int tok = (blockIdx.x << 2) + wave;
    const float* xp = x + (size_t)tok * kC;
    float v0 = xp[lane], v1 = xp[lane + 64], v2 = xp[lane + 128];
    float s  = v0 + v1 + v2;
    float sq = v0 * v0 + v1 * v1 + v2 * v2;
    #pragma unroll
    for (int off = 32; off > 0; off >>= 1) {
        s  += __shfl_down(s, off, 64);
        sq += __shfl_down(sq, off, 64);
    }
    s  = __shfl(s, 0, 64);
    sq = __shfl(sq, 0, 64);
    const float mean = s * (1.0f / kC);
    const float var  = sq * (1.0f / kC) - mean * mean;
    const float inv  = rsqrtf(var + kEps);
    size_t orow;
    if (do_shift) {
        const int b = tok / kL, hw = tok % kL;
        const int h = hw / kW, w = hw % kW;
        const int hs = (h + kH - kSS) % kH;
        const int ws = (w + kW - kSS) % kW;
        const int wh = hs / kWS, ii = hs % kWS;
        const int ww = ws / kWS, jj = ws % kWS;
        orow = (size_t)(b * 64 + wh * 8 + ww) * kN + (ii * kWS + jj);
    } else {
        orow = tok;
    }
    u16* op = out + orow * kC;
    op[lane]       = f2bf((v0 - mean) * inv * gamma[lane]       + beta[lane]);
    op[lane + 64]  = f2bf((v1 - mean) * inv * gamma[lane + 64]  + beta[lane + 64]);
    op[lane + 128] = f2bf((v2 - mean) * inv * gamma[lane + 128] + beta[lane + 128]);
}

// ---------------------------------------------------------------------------
// Weight prep: fp32 K x Nn (k-major) -> bf16 Nn x K (n-major).
// ---------------------------------------------------------------------------
__global__ __launch_bounds__(256) void wprep_qkv(
    const float* __restrict__ w, u16* __restrict__ wt)
{
    const int idx = blockIdx.x * 256 + threadIdx.x;
    if (idx >= 576 * 192) return;
    const int n = idx / 192, k = idx - n * 192;
    wt[idx] = f2bf(w[(size_t)k * 576 + n]);
}

__global__ __launch_bounds__(256) void wprep_rest(
    const float* __restrict__ pw, const float* __restrict__ f1w,
    const float* __restrict__ f2w, u16* __restrict__ proj_t,
    u16* __restrict__ f1_t, u16* __restrict__ f2_t)
{
    int idx = blockIdx.x * 256 + threadIdx.x;
    if (idx < 36864) {
        const int n = idx / 192, k = idx - n * 192;
        proj_t[idx] = f2bf(pw[(size_t)k * 192 + n]);
        return;
    }
    idx -= 36864;
    if (idx < 147456) {
        const int n = idx / 192, k = idx - n * 192;
        f1_t[idx] = f2bf(f1w[(size_t)k * 768 + n]);
        return;
    }
    idx -= 147456;
    if (idx < 147456) {
        const int n = idx / 768, k = idx - n * 768;
        f2_t[idx] = f2bf(f2w[(size_t)k * 192 + n]);
    }
}

// ---------------------------------------------------------------------------
// Bias+mask table: T[cls][head][n][m], cls = (whEdge<<1)|wwEdge.
// ---------------------------------------------------------------------------
__global__ __launch_bounds__(256) void prep_bm(
    const float* __restrict__ btab, float* __restrict__ T)
{
    const int idx = blockIdx.x * 256 + threadIdx.x;
    if (idx >= 4 * 6 * 49 * 49) return;
    const int m = idx % 49, n = (idx / 49) % 49;
    const int head = (idx / 2401) % 6, cls = idx / (2401 * 6);
    const int i1 = n / 7, j1 = n % 7, i2 = m / 7, j2 = m % 7;
    float v = btab[((i1 - i2 + 6) * 13 + (j1 - j2 + 6)) * kNH + head];
    const int whE = cls >> 1, wwE = cls & 1;
    const int r1 = (whE ? (i1 < 4 ? 1 : 2) : 0) * 3 + (wwE ? (j1 < 4 ? 1 : 2) : 0);
    const int r2 = (whE ? (i2 < 4 ? 1 : 2) : 0) * 3 + (wwE ? (j2 < 4 ? 1 : 2) : 0);
    if (r1 != r2) v -= 100.f;
    T[idx] = v;
}

// ---------------------------------------------------------------------------
// MFMA GEMM with LDS-staged A: out(M x Nn) = A_bf16(M x K) @ Bt + bias.
// A-tile (64 x K, contiguous in global) staged ONCE per block into LDS with
// row stride K+8 (quad-lane ds_read_b128 -> bank stride 4 -> free 2-way).
// Reused across NJ j-tiles. B direct from global (L2-resident weights).
// MODE 0: bf16 out   1: GELU bf16 out   2: scatter+residual(aux) fp32 out
// MODE 3: +bias +aux fp32 out           4: accumulate into fp32 out
// ---------------------------------------------------------------------------
template <int MODE, int K, int NJ>
__global__ __launch_bounds__(256) void gemm_mfma(
    const u16* __restrict__ A, const u16* __restrict__ Bt, int ldb,
    const float* __restrict__ bias, const float* __restrict__ aux,
    void* __restrict__ outv)
{
    constexpr int Nn = NJ * 192;
    constexpr int Kp = K + 8;
    __shared__ u16 As[64 * Kp];
    const int tid  = threadIdx.x;
    const int wave = tid >> 6, lane = tid & 63;
    const int quad = lane >> 4, l15 = lane & 15;
    const int m0 = blockIdx.x * 64;

    // ---- stage A tile: contiguous 64*K elems, coalesced, padded rows ----
    {
        const u16* src = A + (size_t)m0 * K;
        #pragma unroll
        for (int i = tid; i < 64 * K / 8; i += 256) {
            const int e = i * 8;
            const int r = e / K, c = e - r * K;
            *(short8*)&As[r * Kp + c] = *(const short8*)(src + e);
        }
    }
    __syncthreads();

    #pragma unroll
    for (int j = 0; j < NJ; ++j) {
        const int nb0 = j * 192 + wave * 48;
        const u16* Bbase = Bt + (size_t)(nb0 + l15) * ldb + quad * 8;
        f32x4 acc[4][3] = {};
        #pragma unroll
        for (int ks = 0; ks < K / 32; ++ks) {
            short8 a[4], b[3];
            #pragma unroll
            for (int i = 0; i < 4; ++i)
                a[i] = *(const short8*)&As[(i * 16 + l15) * Kp + ks * 32 + quad * 8];
            #pragma unroll
            for (int t = 0; t < 3; ++t)
                b[t] = *(const short8*)(Bbase + (size_t)t * 16 * ldb + ks * 32);
            #pragma unroll
            for (int i = 0; i < 4; ++i)
                #pragma unroll
                for (int t = 0; t < 3; ++t)
                    acc[i][t] = __builtin_amdgcn_mfma_f32_16x16x32_bf16(
                        a[i], b[t], acc[i][t], 0, 0, 0);
        }
        float bcol[3] = {0.f, 0.f, 0.f};
        if (MODE != 4) {
            #pragma unroll
            for (int t = 0; t < 3; ++t) bcol[t] = bias[nb0 + t * 16 + l15];
        }
        #pragma unroll
        for (int i = 0; i < 4; ++i) {
            #pragma unroll
            for (int reg = 0; reg < 4; ++reg) {
                const int r = m0 + i * 16 + quad * 4 + reg;
                if (MODE == 2) {
                    const int win = r / kN, n = r % kN;
                    const int b = win >> 6, wi = win & 63;
                    const int wh = wi >> 3, ww = wi & 7;
                    const int i1 = n / kWS, j1 = n % kWS;
                    const int h = (wh * kWS + i1 + kSS) % kH;
                    const int w = (ww * kWS + j1 + kSS) % kW;
                    const size_t drow = ((size_t)b * kL + h * kW + w) * kC;
                    #pragma unroll
                    for (int t = 0; t < 3; ++t) {
                        const int c = nb0 + t * 16 + l15;
                        const size_t dest = drow + c;
                        ((float*)outv)[dest] = acc[i][t][reg] + bcol[t] + aux[dest];
                    }
                } else if (MODE == 3) {
                    #pragma unroll
                    for (int t = 0; t < 3; ++t) {
                        const int c = nb0 + t * 16 + l15;
                        const size_t off = (size_t)r * Nn + c;
                        ((float*)outv)[off] = acc[i][t][reg] + bcol[t] + aux[off];
                    }
                } else if (MODE == 4) {
                    #pragma unroll
                    for (int t = 0; t < 3; ++t) {
                        const int c = nb0 + t * 16 + l15;
                        const size_t off = (size_t)r * Nn + c;
                        ((float*)outv)[off] += acc[i][t][reg];
                    }
                } else {
                    #pragma unroll
                    for (int t = 0; t < 3; ++t) {
                        const int c = nb0 + t * 16 + l15;
                        float v = acc[i][t][reg] + bcol[t];
                        if (MODE == 1)
                            v = 0.5f * v * (1.0f + erff(v * 0.7071067811865476f));
                        ((u16*)outv)[(size_t)r * Nn + c] = f2bf(v);
                    }
                }
            }
        }
    }
}

// ---------------------------------------------------------------------------
// MFMA window attention: ONE WAVE per (window, head). Unchanged from round 4.
// ---------------------------------------------------------------------------
__global__ __launch_bounds__(256) void attn_mfma(
    const u16* __restrict__ qkv, const float* __restrict__ T,
    u16* __restrict__ out)
{
    __shared__ u16 Ps[4][64][72];
    __shared__ u16 Vt[4][32][72];
    const int tid = threadIdx.x;
    const int wave = tid >> 6, lane = tid & 63;
    const int quad = lane >> 4, l15 = lane & 15;
    const int pair = blockIdx.x * 4 + wave;
    const int win = pair / 6, head = pair - win * 6;
    const int wi = win & 63;
    const int cls = (((wi >> 3) == 7) ? 2 : 0) + (((wi & 7) == 7) ? 1 : 0);
    const float* Tb = T + (size_t)(cls * 6 + head) * 49 * 49;

    const u16* base = qkv + (size_t)win * 49 * 576 + head * 32 + quad * 8;
    short8 zz = {};
    short8 qa[4], kb[4];
    #pragma unroll
    for (int i = 0; i < 4; ++i) {
        const int n = i * 16 + l15;
        qa[i] = (n < 49) ? *(const short8*)(base + (size_t)n * 576) : zz;
        kb[i] = (n < 49) ? *(const short8*)(base + (size_t)n * 576 + 192) : zz;
    }
    for (int z = lane; z < 32 * 16; z += 64)
        if (z & 15) Vt[wave][z >> 4][48 + (z & 15)] = 0;
    const u16* vbase = qkv + (size_t)win * 49 * 576 + 384 + head * 32;
    for (int idx = lane; idx < 49 * 16; idx += 64) {
        const int n = idx >> 4, dp = (idx & 15) << 1;
        const u16* p = vbase + (size_t)n * 576 + dp;
        Vt[wave][dp][n]     = p[0];
        Vt[wave][dp + 1][n] = p[1];
    }
    f32x4 acc[4][4] = {};
    #pragma unroll
    for (int i = 0; i < 4; ++i)
        #pragma unroll
        for (int j = 0; j < 4; ++j)
            acc[i][j] = __builtin_amdgcn_mfma_f32_16x16x32_bf16(
                qa[i], kb[j], acc[i][j], 0, 0, 0);
    float rowinv[4][4];
    #pragma unroll
    for (int i = 0; i < 4; ++i) {
        #pragma unroll
        for (int reg = 0; reg < 4; ++reg) {
            const int n = i * 16 + quad * 4 + reg;
            const int nc = (n < 49) ? n : 48;
            float s[4];
            #pragma unroll
            for (int j = 0; j < 4; ++j) {
                const int m = j * 16 + l15;
                s[j] = (m < 49) ? fmaf(acc[i][j][reg], kScale, Tb[nc * 49 + m])
                                : -1e30f;
            }
            float mx = fmaxf(fmaxf(s[0], s[1]), fmaxf(s[2], s[3]));
            #pragma unroll
            for (int off = 1; off < 16; off <<= 1)
                mx = fmaxf(mx, __shfl_xor(mx, off, 64));
            float e0 = __expf(s[0] - mx), e1 = __expf(s[1] - mx);
            float e2 = __expf(s[2] - mx), e3 = __expf(s[3] - mx);
            float sum = e0 + e1 + e2 + e3;
            #pragma unroll
            for (int off = 1; off < 16; off <<= 1)
                sum += __shfl_xor(sum, off, 64);
            rowinv[i][reg] = 1.0f / sum;
            Ps[wave][n][0 * 16 + l15] = f2bf(e0);
            Ps[wave][n][1 * 16 + l15] = f2bf(e1);
            Ps[wave][n][2 * 16 + l15] = f2bf(e2);
            Ps[wave][n][3 * 16 + l15] = f2bf(e3);
        }
    }
    f32x4 o[4][2] = {};
    #pragma unroll
    for (int ks = 0; ks < 2; ++ks) {
        short8 pa[4], vb[2];
        #pragma unroll
        for (int i = 0; i < 4; ++i)
            pa[i] = *(const short8*)&Ps[wave][i * 16 + l15][ks * 32 + quad * 8];
        #pragma unroll
        for (int t = 0; t < 2; ++t)
            vb[t] = *(const short8*)&Vt[wave][t * 16 + l15][ks * 32 + quad * 8];
        #pragma unroll
        for (int i = 0; i < 4; ++i)
            #pragma unroll
            for (int t = 0; t < 2; ++t)
                o[i][t] = __builtin_amdgcn_mfma_f32_16x16x32_bf16(
                    pa[i], vb[t], o[i][t], 0, 0, 0);
    }
    u16* obase = out + (size_t)win * 49 * 192 + head * 32;
    #pragma unroll
    for (int i = 0; i < 4; ++i) {
        #pragma unroll
        for (int reg = 0; reg < 4; ++reg) {
            const int n = i * 16 + quad * 4 + reg;
            if (n < 49) {
                const float inv = rowinv[i][reg];
                obase[(size_t)n * 192 + l15]      = f2bf(o[i][0][reg] * inv);
                obase[(size_t)n * 192 + 16 + l15] = f2bf(o[i][1][reg] * inv);
            }
        }
    }
}

// ---------------------------------------------------------------------------
extern "C" void kernel_launch(void* const* d_in, const int* in_sizes, int n_in,
                              void* d_out, int out_size, void* d_ws, size_t ws_size,
                              hipStream_t stream)
{
    const float* x      = (const float*)d_in[0];
    const float* gamma1 = (const float*)d_in[1];
    const float* beta1  = (const float*)d_in[2];
    const float* qkv_w  = (const float*)d_in[3];
    const float* qkv_b  = (const float*)d_in[4];
    const float* proj_w = (const float*)d_in[5];
    const float* proj_b = (const float*)d_in[6];
    const float* btab   = (const float*)d_in[7];
    const float* gamma2 = (const float*)d_in[8];
    const float* beta2  = (const float*)d_in[9];
    const float* fc1_w  = (const float*)d_in[10];
    const float* fc1_b  = (const float*)d_in[11];
    const float* fc2_w  = (const float*)d_in[12];
    const float* fc2_b  = (const float*)d_in[13];
    float* out = (float*)d_out;

    // ws budget EXACTLY kTok*768*2 B. Scratch in dead regions:
    //   qkv_t + bm table -> start of d_out (dead until proj epilogue)
    //   proj/fc1/fc2 bf16 weights -> tail of buf_b (written after attn)
    u16* buf_a = (u16*)d_ws;                      // kTok*192 bf16
    u16* buf_b = buf_a + (size_t)kTok * 192;      // kTok*576 bf16
    u16* qkv_t = (u16*)d_out;                     // 110592 u16
    float* bm_tab = (float*)d_out + 55296;        // 57624 floats (after qkv_t)
    u16* wt2   = (u16*)d_ws + (size_t)kTok * 768 - 331776;
    u16* proj_t = wt2;
    u16* f1_t   = wt2 + 36864;
    u16* f2_t   = f1_t + 147456;

    // 0) weight + bias/mask table prep (into d_out scratch)
    wprep_qkv<<<(110592 + 255) / 256, 256, 0, stream>>>(qkv_w, qkv_t);
    prep_bm<<<(57624 + 255) / 256, 256, 0, stream>>>(btab, bm_tab);
    // 1) LN1 + cyclic shift + window partition
    ln_kernel<<<kTok / 4, 256, 0, stream>>>(x, gamma1, beta1, buf_a, 1);
    // 2) qkv GEMM -> buf_b (bf16)
    gemm_mfma<0, 192, 3><<<kTok / 64, 256, 0, stream>>>(
        buf_a, qkv_t, 192, qkv_b, nullptr, buf_b);
    // 3) MFMA window attention -> buf_a (bf16)
    attn_mfma<<<(kNWin * kNH) / 4, 256, 0, stream>>>(buf_b, bm_tab, buf_a);
    // 4) remaining weight prep into buf_b tail (qkv dead now)
    wprep_rest<<<(331776 + 255) / 256, 256, 0, stream>>>(
        proj_w, fc1_w, fc2_w, proj_t, f1_t, f2_t);
    // 5) proj GEMM + window reverse + unshift + residual(x) -> x1 in d_out
    gemm_mfma<2, 192, 1><<<kTok / 64, 256, 0, stream>>>(
        buf_a, proj_t, 192, proj_b, x, out);
    // 6) LN2 -> buf_a
    ln_kernel<<<kTok / 4, 256, 0, stream>>>(out, gamma2, beta2, buf_a, 0);
    // 7a) fc1 half 0 + GELU -> buf_b (384-wide bf16)
    gemm_mfma<1, 192, 2><<<kTok / 64, 256, 0, stream>>>(
        buf_a, f1_t, 192, fc1_b, nullptr, buf_b);
    // 8a) fc2 half 0: out = hidden0 @ fc2[0:384] + bias + x1
    gemm_mfma<3, 384, 1><<<kTok / 64, 256, 0, stream>>>(
        buf_b, f2_t, 768, fc2_b, out, out);
    // 7b) fc1 half 1 + GELU -> buf_b
    gemm_mfma<1, 192, 2><<<kTok / 64, 256, 0, stream>>>(
        buf_a, f1_t + (size_t)384 * 192, 192, fc1_b + 384, nullptr, buf_b);
    // 8b) fc2 half 1: out += hidden1 @ fc2[384:768]
    gemm_mfma<4, 384, 1><<<kTok / 64, 256, 0, stream>>>(
        buf_b, f2_t + 384, 768, nullptr, nullptr, out);
}

// Round 6
// 699.651 us; speedup vs baseline: 2.4413x; 1.0028x over previous
//
#include <hip/hip_runtime.h>
#include <math.h>

namespace {
constexpr int kBatch = 32, kH = 56, kW = 56, kC = 192, kNH = 6, kWS = 7, kSS = 3;
constexpr int kL   = kH * kW;        // 3136
constexpr int kN   = kWS * kWS;      // 49
constexpr int kTok = kBatch * kL;    // 100352
constexpr int kNWin = kTok / kN;     // 2048 windows
constexpr float kEps   = 1e-3f;
constexpr float kScale = 0.17677669529663687f;  // HD^-0.5
}

typedef unsigned short u16;
typedef __attribute__((ext_vector_type(8))) short short8;   // 8 x bf16 (4 VGPRs)
typedef __attribute__((ext_vector_type(4))) float f32x4;    // MFMA accumulator

__device__ __forceinline__ float bf2f(u16 u) {
    return __uint_as_float(((unsigned int)u) << 16);
}
__device__ __forceinline__ u16 f2bf(float f) {  // round-to-nearest-even
    unsigned int x = __float_as_uint(f);
    return (u16)((x + 0x7FFFu + ((x >> 16) & 1u)) >> 16);
}

// ---------------------------------------------------------------------------
// LayerNorm over C=192 (fp32 in, bf16 out), one wave per token.
// ---------------------------------------------------------------------------
__global__ __launch_bounds__(256) void ln_kernel(
    const float* __restrict__ x, const float* __restrict__ gamma,
    const float* __restrict__ beta, u16* __restrict__ out, int do_shift)
{
    const int wave = threadIdx.x >> 6;
    const int lane = threadIdx.x & 63;
    const int tok = (blockIdx.x << 2) + wave;
    const float* xp = x + (size_t)tok * kC;
    float v0 = xp[lane], v1 = xp[lane + 64], v2 = xp[lane + 128];
    float s  = v0 + v1 + v2;
    float sq = v0 * v0 + v1 * v1 + v2 * v2;
    #pragma unroll
    for (int off = 32; off > 0; off >>= 1) {
        s  += __shfl_down(s, off, 64);
        sq += __shfl_down(sq, off, 64);
    }
    s  = __shfl(s, 0, 64);
    sq = __shfl(sq, 0, 64);
    const float mean = s * (1.0f / kC);
    const float var  = sq * (1.0f / kC) - mean * mean;
    const float inv  = rsqrtf(var + kEps);
    size_t orow;
    if (do_shift) {
        const int b = tok / kL, hw = tok % kL;
        const int h = hw / kW, w = hw % kW;
        const int hs = (h + kH - kSS) % kH;
        const int ws = (w + kW - kSS) % kW;
        const int wh = hs / kWS, ii = hs % kWS;
        const int ww = ws / kWS, jj = ws % kWS;
        orow = (size_t)(b * 64 + wh * 8 + ww) * kN + (ii * kWS + jj);
    } else {
        orow = tok;
    }
    u16* op = out + orow * kC;
    op[lane]       = f2bf((v0 - mean) * inv * gamma[lane]       + beta[lane]);
    op[lane + 64]  = f2bf((v1 - mean) * inv * gamma[lane + 64]  + beta[lane + 64]);
    op[lane + 128] = f2bf((v2 - mean) * inv * gamma[lane + 128] + beta[lane + 128]);
}

// ---------------------------------------------------------------------------
// Weight prep. qkv: fp32 (192 x 576) -> bf16 n-major (576 x 192), q-cols
// pre-scaled by kScale.
// ---------------------------------------------------------------------------
__global__ __launch_bounds__(256) void wprep_qkv(
    const float* __restrict__ w, u16* __restrict__ wt)
{
    const int idx = blockIdx.x * 256 + threadIdx.x;
    if (idx >= 576 * 192) return;
    const int n = idx / 192, k = idx - n * 192;
    float v = w[(size_t)k * 576 + n];
    if (n < 192) v *= kScale;
    wt[idx] = f2bf(v);
}

__global__ __launch_bounds__(256) void wprep_rest(
    const float* __restrict__ pw, const float* __restrict__ f1w,
    const float* __restrict__ f2w, u16* __restrict__ proj_t,
    u16* __restrict__ f1_t, u16* __restrict__ f2_t)
{
    int idx = blockIdx.x * 256 + threadIdx.x;
    if (idx < 36864) {
        const int n = idx / 192, k = idx - n * 192;
        proj_t[idx] = f2bf(pw[(size_t)k * 192 + n]);
        return;
    }
    idx -= 36864;
    if (idx < 147456) {
        const int n = idx / 192, k = idx - n * 192;
        f1_t[idx] = f2bf(f1w[(size_t)k * 768 + n]);
        return;
    }
    idx -= 147456;
    if (idx < 147456) {
        const int n = idx / 768, k = idx - n * 768;
        f2_t[idx] = f2bf(f2w[(size_t)k * 192 + n]);
    }
}

// ---------------------------------------------------------------------------
// Bias+mask table T[cls][head][n][m] (mask folded, used as MFMA C-init) and
// scaled qkv bias copy (q-part * kScale).
// ---------------------------------------------------------------------------
__global__ __launch_bounds__(256) void prep_bm(
    const float* __restrict__ btab, const float* __restrict__ qkv_b,
    float* __restrict__ T, float* __restrict__ qkv_bs)
{
    const int idx = blockIdx.x * 256 + threadIdx.x;
    if (idx < 576) qkv_bs[idx] = (idx < 192) ? qkv_b[idx] * kScale : qkv_b[idx];
    if (idx >= 4 * 6 * 49 * 49) return;
    const int m = idx % 49, n = (idx / 49) % 49;
    const int head = (idx / 2401) % 6, cls = idx / (2401 * 6);
    const int i1 = n / 7, j1 = n % 7, i2 = m / 7, j2 = m % 7;
    float v = btab[((i1 - i2 + 6) * 13 + (j1 - j2 + 6)) * kNH + head];
    const int whE = cls >> 1, wwE = cls & 1;
    const int r1 = (whE ? (i1 < 4 ? 1 : 2) : 0) * 3 + (wwE ? (j1 < 4 ? 1 : 2) : 0);
    const int r2 = (whE ? (i2 < 4 ? 1 : 2) : 0) * 3 + (wwE ? (j2 < 4 ? 1 : 2) : 0);
    if (r1 != r2) v -= 100.f;
    T[idx] = v;
}

// ---------------------------------------------------------------------------
// MFMA GEMM with LDS-staged A: out(M x Nn) = A_bf16(M x K) @ Bt + bias.
// MODE 0: bf16 out   1: GELU bf16 out   2: scatter+residual(aux) fp32 out
// MODE 3: +bias +aux fp32 out           4: accumulate into fp32 out
// MODE 5 (qkv): j<2 -> bf16 q,k into rows of 576; j==2 -> scatter v
//               TRANSPOSED into vt[(win*6+head)*32 + d][64] (aux2).
// ---------------------------------------------------------------------------
template <int MODE, int K, int NJ>
__global__ __launch_bounds__(256) void gemm_mfma(
    const u16* __restrict__ A, const u16* __restrict__ Bt, int ldb,
    const float* __restrict__ bias, const float* __restrict__ aux,
    void* __restrict__ outv, u16* __restrict__ vt = nullptr)
{
    constexpr int Nn = NJ * 192;
    constexpr int Kp = K + 8;
    __shared__ u16 As[64 * Kp];
    const int tid  = threadIdx.x;
    const int wave = tid >> 6, lane = tid & 63;
    const int quad = lane >> 4, l15 = lane & 15;
    const int m0 = blockIdx.x * 64;

    {
        const u16* src = A + (size_t)m0 * K;
        #pragma unroll
        for (int i = tid; i < 64 * K / 8; i += 256) {
            const int e = i * 8;
            const int r = e / K, c = e - r * K;
            *(short8*)&As[r * Kp + c] = *(const short8*)(src + e);
        }
    }
    __syncthreads();

    #pragma unroll
    for (int j = 0; j < NJ; ++j) {
        const int nb0 = j * 192 + wave * 48;
        const u16* Bbase = Bt + (size_t)(nb0 + l15) * ldb + quad * 8;
        f32x4 acc[4][3] = {};
        #pragma unroll
        for (int ks = 0; ks < K / 32; ++ks) {
            short8 a[4], b[3];
            #pragma unroll
            for (int i = 0; i < 4; ++i)
                a[i] = *(const short8*)&As[(i * 16 + l15) * Kp + ks * 32 + quad * 8];
            #pragma unroll
            for (int t = 0; t < 3; ++t)
                b[t] = *(const short8*)(Bbase + (size_t)t * 16 * ldb + ks * 32);
            #pragma unroll
            for (int i = 0; i < 4; ++i)
                #pragma unroll
                for (int t = 0; t < 3; ++t)
                    acc[i][t] = __builtin_amdgcn_mfma_f32_16x16x32_bf16(
                        a[i], b[t], acc[i][t], 0, 0, 0);
        }
        float bcol[3] = {0.f, 0.f, 0.f};
        if (MODE != 4) {
            #pragma unroll
            for (int t = 0; t < 3; ++t) bcol[t] = bias[nb0 + t * 16 + l15];
        }
        #pragma unroll
        for (int i = 0; i < 4; ++i) {
            #pragma unroll
            for (int reg = 0; reg < 4; ++reg) {
                const int r = m0 + i * 16 + quad * 4 + reg;
                if (MODE == 2) {
                    const int win = r / kN, n = r % kN;
                    const int b = win >> 6, wi = win & 63;
                    const int wh = wi >> 3, ww = wi & 7;
                    const int i1 = n / kWS, j1 = n % kWS;
                    const int h = (wh * kWS + i1 + kSS) % kH;
                    const int w = (ww * kWS + j1 + kSS) % kW;
                    const size_t drow = ((size_t)b * kL + h * kW + w) * kC;
                    #pragma unroll
                    for (int t = 0; t < 3; ++t) {
                        const int c = nb0 + t * 16 + l15;
                        const size_t dest = drow + c;
                        ((float*)outv)[dest] = acc[i][t][reg] + bcol[t] + aux[dest];
                    }
                } else if (MODE == 3) {
                    #pragma unroll
                    for (int t = 0; t < 3; ++t) {
                        const int c = nb0 + t * 16 + l15;
                        const size_t off = (size_t)r * Nn + c;
                        ((float*)outv)[off] = acc[i][t][reg] + bcol[t] + aux[off];
                    }
                } else if (MODE == 4) {
                    #pragma unroll
                    for (int t = 0; t < 3; ++t) {
                        const int c = nb0 + t * 16 + l15;
                        const size_t off = (size_t)r * Nn + c;
                        ((float*)outv)[off] += acc[i][t][reg];
                    }
                } else if (MODE == 5 && j == 2) {
                    // scatter v transposed: row win*6*32 + head*32 + d, col n
                    const int win = r / kN, n = r - win * kN;
                    #pragma unroll
                    for (int t = 0; t < 3; ++t) {
                        const int d = nb0 - 384 + t * 16 + l15;
                        const size_t off =
                            ((size_t)win * 192 + d) * 64 + n;  // 192 = 6*32
                        vt[off] = f2bf(acc[i][t][reg] + bcol[t]);
                    }
                } else {
                    #pragma unroll
                    for (int t = 0; t < 3; ++t) {
                        const int c = nb0 + t * 16 + l15;
                        float v = acc[i][t][reg] + bcol[t];
                        if (MODE == 1)
                            v = 0.5f * v * (1.0f + erff(v * 0.7071067811865476f));
                        ((u16*)outv)[(size_t)r * Nn + c] = f2bf(v);
                    }
                }
            }
        }
    }
}

// ---------------------------------------------------------------------------
// MFMA window attention v2: ONE WAVE per (window, head).
// S = QK^T with C-init = bias+mask table (q pre-scaled in GEMM). No
// max-subtraction (logits bounded). P -> LDS; PV B-frags straight from the
// transposed-V buffer written by the qkv GEMM. No Vt LDS, no barriers.
// ---------------------------------------------------------------------------
__global__ __launch_bounds__(256) void attn_mfma(
    const u16* __restrict__ qkv, const u16* __restrict__ vt,
    const float* __restrict__ T, u16* __restrict__ out)
{
    __shared__ u16 Ps[4][64][72];
    const int tid = threadIdx.x;
    const int wave = tid >> 6, lane = tid & 63;
    const int quad = lane >> 4, l15 = lane & 15;
    const int pair = blockIdx.x * 4 + wave;
    const int win = pair / 6, head = pair - win * 6;
    const int wi = win & 63;
    const int cls = (((wi >> 3) == 7) ? 2 : 0) + (((wi & 7) == 7) ? 1 : 0);
    const float* Tb = T + (size_t)(cls * 6 + head) * 49 * 49;

    // --- load Q,K fragments ---
    const u16* base = qkv + (size_t)win * 49 * 576 + head * 32 + quad * 8;
    short8 zz = {};
    short8 qa[4], kb[4];
    #pragma unroll
    for (int i = 0; i < 4; ++i) {
        const int n = i * 16 + l15;
        qa[i] = (n < 49) ? *(const short8*)(base + (size_t)n * 576) : zz;
        kb[i] = (n < 49) ? *(const short8*)(base + (size_t)n * 576 + 192) : zz;
    }
    // --- C-init = bias+mask table; pad cols (m>=49) = -30000 -> exp = 0 ---
    f32x4 acc[4][4];
    #pragma unroll
    for (int i = 0; i < 4; ++i) {
        #pragma unroll
        for (int reg = 0; reg < 4; ++reg) {
            const int n = i * 16 + quad * 4 + reg;
            const bool nv = (n < 49);
            const float* Trow = Tb + (nv ? n : 0) * 49;
            #pragma unroll
            for (int j = 0; j < 3; ++j)
                acc[i][j][reg] = nv ? Trow[j * 16 + l15] : 0.f;
            acc[i][3][reg] = (nv && l15 == 0) ? Trow[48] : -30000.f;
        }
    }
    // --- S = Q @ K^T + C ---
    #pragma unroll
    for (int i = 0; i < 4; ++i)
        #pragma unroll
        for (int j = 0; j < 4; ++j)
            acc[i][j] = __builtin_amdgcn_mfma_f32_16x16x32_bf16(
                qa[i], kb[j], acc[i][j], 0, 0, 0);
    // --- softmax (no max-shift), P -> LDS ---
    float rowinv[4][4];
    #pragma unroll
    for (int i = 0; i < 4; ++i) {
        #pragma unroll
        for (int reg = 0; reg < 4; ++reg) {
            const int n = i * 16 + quad * 4 + reg;
            float e0 = __expf(acc[i][0][reg]), e1 = __expf(acc[i][1][reg]);
            float e2 = __expf(acc[i][2][reg]), e3 = __expf(acc[i][3][reg]);
            float sum = e0 + e1 + e2 + e3;
            #pragma unroll
            for (int off = 1; off < 16; off <<= 1)
                sum += __shfl_xor(sum, off, 64);
            rowinv[i][reg] = 1.0f / sum;
            Ps[wave][n][0 * 16 + l15] = f2bf(e0);
            Ps[wave][n][1 * 16 + l15] = f2bf(e1);
            Ps[wave][n][2 * 16 + l15] = f2bf(e2);
            Ps[wave][n][3 * 16 + l15] = f2bf(e3);
        }
    }
    // --- O = P @ V: B-frags direct from vt[(pair*32 + d)*64 + m] ---
    const u16* vb_base = vt + ((size_t)pair * 32 + l15) * 64 + quad * 8;
    f32x4 o[4][2] = {};
    #pragma unroll
    for (int ks = 0; ks < 2; ++ks) {
        short8 pa[4], vb[2];
        #pragma unroll
        for (int i = 0; i < 4; ++i)
            pa[i] = *(const short8*)&Ps[wave][i * 16 + l15][ks * 32 + quad * 8];
        #pragma unroll
        for (int t = 0; t < 2; ++t)
            vb[t] = *(const short8*)(vb_base + (size_t)t * 16 * 64 + ks * 32);
        #pragma unroll
        for (int i = 0; i < 4; ++i)
            #pragma unroll
            for (int t = 0; t < 2; ++t)
                o[i][t] = __builtin_amdgcn_mfma_f32_16x16x32_bf16(
                    pa[i], vb[t], o[i][t], 0, 0, 0);
    }
    // --- epilogue ---
    u16* obase = out + (size_t)win * 49 * 192 + head * 32;
    #pragma unroll
    for (int i = 0; i < 4; ++i) {
        #pragma unroll
        for (int reg = 0; reg < 4; ++reg) {
            const int n = i * 16 + quad * 4 + reg;
            if (n < 49) {
                const float inv = rowinv[i][reg];
                obase[(size_t)n * 192 + l15]      = f2bf(o[i][0][reg] * inv);
                obase[(size_t)n * 192 + 16 + l15] = f2bf(o[i][1][reg] * inv);
            }
        }
    }
}

// ---------------------------------------------------------------------------
extern "C" void kernel_launch(void* const* d_in, const int* in_sizes, int n_in,
                              void* d_out, int out_size, void* d_ws, size_t ws_size,
                              hipStream_t stream)
{
    const float* x      = (const float*)d_in[0];
    const float* gamma1 = (const float*)d_in[1];
    const float* beta1  = (const float*)d_in[2];
    const float* qkv_w  = (const float*)d_in[3];
    const float* qkv_b  = (const float*)d_in[4];
    const float* proj_w = (const float*)d_in[5];
    const float* proj_b = (const float*)d_in[6];
    const float* btab   = (const float*)d_in[7];
    const float* gamma2 = (const float*)d_in[8];
    const float* beta2  = (const float*)d_in[9];
    const float* fc1_w  = (const float*)d_in[10];
    const float* fc1_b  = (const float*)d_in[11];
    const float* fc2_w  = (const float*)d_in[12];
    const float* fc2_b  = (const float*)d_in[13];
    float* out = (float*)d_out;

    // ws budget EXACTLY kTok*768*2 B. d_out (77 MB fp32) doubles as scratch
    // until the proj epilogue: qkv_t | bm_tab | qkv_bs | vT(50.3 MB).
    u16* buf_a = (u16*)d_ws;                      // kTok*192 bf16
    u16* buf_b = buf_a + (size_t)kTok * 192;      // kTok*576 bf16 (q,k used)
    u16* qkv_t = (u16*)d_out;                     // 110592 u16
    float* bm_tab = (float*)d_out + 55296;        // 57624 f32
    float* qkv_bs = bm_tab + 57624;               // 576 f32
    u16* vT = (u16*)d_out + 230400;               // 2048*6*32*64 u16, 16B-aligned
    u16* wt2   = (u16*)d_ws + (size_t)kTok * 768 - 331776;
    u16* proj_t = wt2;
    u16* f1_t   = wt2 + 36864;
    u16* f2_t   = f1_t + 147456;

    // 0) prep: qkv weights (q pre-scaled), bias+mask table, scaled qkv bias
    wprep_qkv<<<(110592 + 255) / 256, 256, 0, stream>>>(qkv_w, qkv_t);
    prep_bm<<<(57624 + 255) / 256, 256, 0, stream>>>(btab, qkv_b, bm_tab, qkv_bs);
    // 1) LN1 + cyclic shift + window partition
    ln_kernel<<<kTok / 4, 256, 0, stream>>>(x, gamma1, beta1, buf_a, 1);
    // 2) qkv GEMM -> q,k rows in buf_b; v scattered transposed into vT
    gemm_mfma<5, 192, 3><<<kTok / 64, 256, 0, stream>>>(
        buf_a, qkv_t, 192, qkv_bs, nullptr, buf_b, vT);
    // 3) MFMA window attention -> buf_a (bf16)
    attn_mfma<<<(kNWin * kNH) / 4, 256, 0, stream>>>(buf_b, vT, bm_tab, buf_a);
    // 4) remaining weight prep into buf_b tail (qkv dead now)
    wprep_rest<<<(331776 + 255) / 256, 256, 0, stream>>>(
        proj_w, fc1_w, fc2_w, proj_t, f1_t, f2_t);
    // 5) proj GEMM + window reverse + unshift + residual(x) -> x1 in d_out
    gemm_mfma<2, 192, 1><<<kTok / 64, 256, 0, stream>>>(
        buf_a, proj_t, 192, proj_b, x, out);
    // 6) LN2 -> buf_a
    ln_kernel<<<kTok / 4, 256, 0, stream>>>(out, gamma2, beta2, buf_a, 0);
    // 7a) fc1 half 0 + GELU -> buf_b (384-wide bf16)
    gemm_mfma<1, 192, 2><<<kTok / 64, 256, 0, stream>>>(
        buf_a, f1_t, 192, fc1_b, nullptr, buf_b);
    // 8a) fc2 half 0: out = hidden0 @ fc2[0:384] + bias + x1
    gemm_mfma<3, 384, 1><<<kTok / 64, 256, 0, stream>>>(
        buf_b, f2_t, 768, fc2_b, out, out);
    // 7b) fc1 half 1 + GELU -> buf_b
    gemm_mfma<1, 192, 2><<<kTok / 64, 256, 0, stream>>>(
        buf_a, f1_t + (size_t)384 * 192, 192, fc1_b + 384, nullptr, buf_b);
    // 8b) fc2 half 1: out += hidden1 @ fc2[384:768]
    gemm_mfma<4, 384, 1><<<kTok / 64, 256, 0, stream>>>(
        buf_b, f2_t + 384, 768, nullptr, nullptr, out);
}